// Round 6
// baseline (580.469 us; speedup 1.0000x reference)
//
#include <hip/hip_runtime.h>
#include <cstdint>
#include <cstddef>

#define NT 256
#define DFEAT 128
#define SCAN_ELEMS 1024
#define CTRL_FLAG 0x40000000
#define SRC_MASK  0x3fffffff

typedef __attribute__((ext_vector_type(8))) short s8v;
typedef __attribute__((ext_vector_type(4))) float f32x4;

__device__ inline ushort f2bf(float f) {           // RNE fp32 -> bf16
  uint32_t u = __float_as_uint(f);
  u += 0x7fffu + ((u >> 16) & 1u);
  return (ushort)(u >> 16);
}

// ---------- zero int array ----------
__global__ void zero_k(int* __restrict__ p, int n) {
  int i = blockIdx.x * NT + threadIdx.x;
  if (i < n) p[i] = 0;
}

// ---------- histogram of dst, both graphs in one dispatch ----------
__global__ void hist2_k(const int* __restrict__ e_dst, int E,
                        const int* __restrict__ c_dst, int EC,
                        int* __restrict__ cnt_c, int* __restrict__ cnt_t) {
  int i = blockIdx.x * NT + threadIdx.x;
  if (i < E) atomicAdd(&cnt_c[e_dst[i]], 1);
  else if (i < E + EC) atomicAdd(&cnt_t[c_dst[i - E]], 1);
}

// ---------- dinv_all[0..n) = conv, [n..2n) = ctrl (from histogram counts) ----------
__global__ void dinv2_k(const int* __restrict__ cntc, const int* __restrict__ cntt,
                        float* __restrict__ dall, int n) {
  int i = blockIdx.x * NT + threadIdx.x;
  if (i < n) {
    dall[i]     = rsqrtf((float)(cntc[i] + 1));
    dall[n + i] = rsqrtf((float)(cntt[i] + 1));
  }
}

// ---------- merged scan pass A: per-block sums of (cnt_c + cnt_t) ----------
__global__ __launch_bounds__(NT) void scan_partial_m(
    const int* __restrict__ cnt_c, const int* __restrict__ cnt_t, int n,
    int* __restrict__ bsum) {
  int base = blockIdx.x * SCAN_ELEMS + threadIdx.x * 4;
  int s = 0;
  if (base + 3 < n) {
    int4 a = *(const int4*)&cnt_c[base];
    int4 b = *(const int4*)&cnt_t[base];
    s = a.x + a.y + a.z + a.w + b.x + b.y + b.z + b.w;
  } else {
    for (int j = 0; j < 4; j++) if (base + j < n) s += cnt_c[base + j] + cnt_t[base + j];
  }
  for (int off = 32; off > 0; off >>= 1) s += __shfl_down(s, off, 64);
  __shared__ int ws[4];
  int lane = threadIdx.x & 63, w = threadIdx.x >> 6;
  if (lane == 0) ws[w] = s;
  __syncthreads();
  if (threadIdx.x == 0) bsum[blockIdx.x] = ws[0] + ws[1] + ws[2] + ws[3];
}

// ---------- merged scan pass B: exclusive prefix over block sums ----------
__global__ __launch_bounds__(NT) void scan_offsets_m(
    int* __restrict__ bsum, int nb, int* __restrict__ rp, int n) {
  __shared__ int ls[NT];
  int t = threadIdx.x;
  int v = (t < nb) ? bsum[t] : 0;
  ls[t] = v;
  __syncthreads();
  for (int off = 1; off < NT; off <<= 1) {
    int u = (t >= off) ? ls[t - off] : 0;
    __syncthreads();
    ls[t] += u;
    __syncthreads();
  }
  if (t < nb) bsum[t] = ls[t] - v;
  if (t == nb - 1) rp[n] = ls[t];
}

// ---------- merged scan pass C: rowptr + cursor (cnt_c becomes fill cursor) ----------
__global__ __launch_bounds__(NT) void scan_final_m(
    int* __restrict__ cnt_c, const int* __restrict__ cnt_t, int n,
    const int* __restrict__ bsum, int* __restrict__ rp) {
  int offset = bsum[blockIdx.x];
  int base = blockIdx.x * SCAN_ELEMS + threadIdx.x * 4;

  int4 v = make_int4(0, 0, 0, 0);
  if (base + 3 < n) {
    int4 a = *(const int4*)&cnt_c[base];
    int4 b = *(const int4*)&cnt_t[base];
    v = make_int4(a.x + b.x, a.y + b.y, a.z + b.z, a.w + b.w);
  } else {
    if (base + 0 < n) v.x = cnt_c[base + 0] + cnt_t[base + 0];
    if (base + 1 < n) v.y = cnt_c[base + 1] + cnt_t[base + 1];
    if (base + 2 < n) v.z = cnt_c[base + 2] + cnt_t[base + 2];
    if (base + 3 < n) v.w = cnt_c[base + 3] + cnt_t[base + 3];
  }
  int tsum = v.x + v.y + v.z + v.w;

  __shared__ int ls[NT];
  int t = threadIdx.x;
  ls[t] = tsum;
  __syncthreads();
  for (int off = 1; off < NT; off <<= 1) {
    int u = (t >= off) ? ls[t - off] : 0;
    __syncthreads();
    ls[t] += u;
    __syncthreads();
  }
  int excl = offset + ls[t] - tsum;

  int4 o;
  o.x = excl;
  o.y = o.x + v.x;
  o.z = o.y + v.y;
  o.w = o.z + v.z;
  if (base + 3 < n) {
    *(int4*)&rp[base] = o;
    *(int4*)&cnt_c[base] = o;   // cursor = absolute row start
  } else {
    if (base + 0 < n) { rp[base + 0] = o.x; cnt_c[base + 0] = o.x; }
    if (base + 1 < n) { rp[base + 1] = o.y; cnt_c[base + 1] = o.y; }
    if (base + 2 < n) { rp[base + 2] = o.z; cnt_c[base + 2] = o.z; }
    if (base + 3 < n) { rp[base + 3] = o.w; cnt_c[base + 3] = o.w; }
  }
}

// ---------- fill merged CSR, 1 edge/thread ----------
__global__ void fill_k(const int* __restrict__ e_src, const int* __restrict__ e_dst, int E,
                       const int* __restrict__ c_src, const int* __restrict__ c_dst, int EC,
                       int* __restrict__ cur, int* __restrict__ csr) {
  int i = blockIdx.x * NT + threadIdx.x;
  if (i < E) {
    csr[atomicAdd(&cur[e_dst[i]], 1)] = e_src[i];
  } else if (i < E + EC) {
    int j = i - E;
    csr[atomicAdd(&cur[c_dst[j]], 1)] = c_src[j] | CTRL_FLAG;
  }
}

// ---------- per-edge signed weight: wv[e] = (+/-) dinv[src] (ctrl = negative) ----------
__global__ void wv_k(const int* __restrict__ csr, const float* __restrict__ dall,
                     float* __restrict__ wv, int etot, int n) {
  int i = blockIdx.x * NT + threadIdx.x;
  if (i < etot) {
    int v = csr[i];
    int s = v & SRC_MASK;
    int f = (v >> 30) & 1;
    float w = dall[s + f * n];
    wv[i] = f ? -w : w;
  }
}

// ---------- x fp32 -> bf16 ----------
__global__ void convx_k(const float* __restrict__ x, ushort* __restrict__ xh, int total4) {
  int i = blockIdx.x * NT + threadIdx.x;
  if (i < total4) {
    float4 v = ((const float4*)x)[i];
    ushort4 o;
    o.x = f2bf(v.x); o.y = f2bf(v.y); o.z = f2bf(v.z); o.w = f2bf(v.w);
    ((ushort4*)xh)[i] = o;
  }
}

// ---------- W fp32 [l][k][c] -> bf16 transposed wT[l][c][k] ----------
__global__ void convw_k(const float* __restrict__ Wc, const float* __restrict__ Wt,
                        ushort* __restrict__ wT) {
  int gid = blockIdx.x * NT + threadIdx.x;
  int l = gid >> 14, rem = gid & 16383;
  int c = rem >> 7, k = rem & 127;
  const float* W = (l < 4) ? (Wc + (size_t)l * 16384) : (Wt + (size_t)(l - 4) * 16384);
  wT[gid] = f2bf(W[k * DFEAT + c]);
}

// ---------- FUSED aggregate + dual-GEMM per 64-node tile ----------
// Phase 1: 8 groups x 8 nodes gather (merged CSR, chunk-8, precomputed signed wv)
//          -> bf16 LDS tile Ag[64][256] (conv cols 0..127 | ctrl 128..255),
//          XOR-swizzled (^(row&7)<<3 ushorts) for phase-2 ds_read_b128.
// Phase 2: 4 waves x 16 rows, K=256 MFMA GEMM; W fragments streamed from L2
//          (wT is 64KB, fully L2-resident); bias+relu fused; writes layer output.
// xh is ping-ponged across layers (blocks race on a shared in/out buffer otherwise).
__global__ __launch_bounds__(256, 4) void aggemm_k(
    const ushort* __restrict__ xin,
    const int* __restrict__ rp, const int* __restrict__ cs, const float* __restrict__ wv,
    const float* __restrict__ dall,
    const ushort* __restrict__ wTc, const ushort* __restrict__ wTt,
    const float* __restrict__ bc, const float* __restrict__ bt,
    float* __restrict__ outf, ushort* __restrict__ outh, int n, int last) {
  __shared__ __align__(16) ushort Ag[64 * 256];   // 32 KB
  __shared__ float bias[DFEAT];
  int tid = threadIdx.x;
  int base = blockIdx.x * 64;

  if (tid < DFEAT) bias[tid] = bc[tid] + bt[tid];

  // ---- phase 1: gather ----
  int grp = tid >> 5, lane = tid & 31, c4 = lane << 2;
  for (int i = 0; i < 8; i++) {
    int r = grp * 8 + i;                 // local row 0..63
    int node = base + r;
    float a0 = 0.f, a1 = 0.f, a2 = 0.f, a3 = 0.f;
    float b0 = 0.f, b1 = 0.f, b2 = 0.f, b3 = 0.f;
    if (node < n) {
      float dc = dall[node], dt = dall[n + node];
      uint2 sv0 = *(const uint2*)&xin[(size_t)node * DFEAT + c4];
      float x0 = __uint_as_float(sv0.x << 16);
      float x1 = __uint_as_float(sv0.x & 0xffff0000u);
      float x2 = __uint_as_float(sv0.y << 16);
      float x3 = __uint_as_float(sv0.y & 0xffff0000u);
      a0 = dc * x0; a1 = dc * x1; a2 = dc * x2; a3 = dc * x3;
      b0 = dt * x0; b1 = dt * x1; b2 = dt * x2; b3 = dt * x3;

      int s0 = rp[node], deg = rp[node + 1] - s0;
      for (int p = 0; p < deg; p += 32) {
        int rem = deg - p;                     // > 0
        int mm = min(32, rem);
        int idx = s0 + p + min(lane, rem - 1); // clamped: always valid
        int sv = cs[idx] & SRC_MASK;
        float wl = wv[idx];
        float ws = (lane < mm) ? wl : 0.f;
        for (int k = 0; k < mm; k += 8) {
          int s[8]; float w[8];
#pragma unroll
          for (int j = 0; j < 8; j++) {
            s[j] = __shfl(sv, k + j, 32);
            w[j] = __shfl(ws, k + j, 32);
          }
          uint2 rr[8];
#pragma unroll
          for (int j = 0; j < 8; j++) rr[j] = *(const uint2*)&xin[(size_t)s[j] * DFEAT + c4];
#pragma unroll
          for (int j = 0; j < 8; j++) {
            float wa = fmaxf(w[j], 0.f);       // conv edges: +w
            float wb = fmaxf(-w[j], 0.f);      // ctrl edges: -w
            float e0 = __uint_as_float(rr[j].x << 16);
            float e1 = __uint_as_float(rr[j].x & 0xffff0000u);
            float e2 = __uint_as_float(rr[j].y << 16);
            float e3 = __uint_as_float(rr[j].y & 0xffff0000u);
            a0 = fmaf(wa, e0, a0); a1 = fmaf(wa, e1, a1);
            a2 = fmaf(wa, e2, a2); a3 = fmaf(wa, e3, a3);
            b0 = fmaf(wb, e0, b0); b1 = fmaf(wb, e1, b1);
            b2 = fmaf(wb, e2, b2); b3 = fmaf(wb, e3, b3);
          }
        }
      }
      a0 *= dc; a1 *= dc; a2 *= dc; a3 *= dc;
      b0 *= dt; b1 *= dt; b2 *= dt; b3 *= dt;
    }
    int swz = (r & 7) << 3;                    // ushort-granule XOR (16B units)
    ushort4 ha, hb;
    ha.x = f2bf(a0); ha.y = f2bf(a1); ha.z = f2bf(a2); ha.w = f2bf(a3);
    hb.x = f2bf(b0); hb.y = f2bf(b1); hb.z = f2bf(b2); hb.w = f2bf(b3);
    *(ushort4*)&Ag[r * 256 + ((lane * 4) ^ swz)] = ha;          // conv half
    *(ushort4*)&Ag[r * 256 + 128 + ((lane * 4) ^ swz)] = hb;    // ctrl half
  }
  __syncthreads();

  // ---- phase 2: 64x128 GEMM, K=256 ----
  int wave = tid >> 6, l64 = tid & 63;
  int m = l64 & 15, q = l64 >> 4;
  int r = wave * 16 + m;                       // local row this lane covers
  int swz = (r & 7) << 3;

  f32x4 zero4 = {0.f, 0.f, 0.f, 0.f};
  f32x4 acc[8];
#pragma unroll
  for (int i = 0; i < 8; i++) acc[i] = zero4;

#pragma unroll 1
  for (int ks = 0; ks < 8; ks++) {
    int kk = ks & 3;
    const ushort* wTh = (ks < 4) ? wTc : wTt;
    union { uint4 u; s8v s; } uA;
    uA.u = *(const uint4*)&Ag[r * 256 + (ks >> 2) * 128 + ((kk * 32 + q * 8) ^ swz)];
    s8v uW[8];
#pragma unroll
    for (int c8 = 0; c8 < 8; c8++)
      uW[c8] = *(const s8v*)&wTh[(size_t)(c8 * 16 + m) * DFEAT + kk * 32 + q * 8];
#pragma unroll
    for (int c8 = 0; c8 < 8; c8++)
      acc[c8] = __builtin_amdgcn_mfma_f32_16x16x32_bf16(uW[c8], uA.s, acc[c8], 0, 0, 0);
  }

  int orow = base + r;
  if (orow < n) {
#pragma unroll
    for (int c8 = 0; c8 < 8; c8++) {
      int col = c8 * 16 + q * 4;
      float4 bv = *(const float4*)&bias[col];
      float o0 = acc[c8][0] + bv.x, o1 = acc[c8][1] + bv.y;
      float o2 = acc[c8][2] + bv.z, o3 = acc[c8][3] + bv.w;
      if (last) {
        *(float4*)&outf[(size_t)orow * DFEAT + col] = make_float4(o0, o1, o2, o3);
      } else {
        ushort4 h;
        h.x = f2bf(fmaxf(o0, 0.f));
        h.y = f2bf(fmaxf(o1, 0.f));
        h.z = f2bf(fmaxf(o2, 0.f));
        h.w = f2bf(fmaxf(o3, 0.f));
        *(ushort4*)&outh[(size_t)orow * DFEAT + col] = h;
      }
    }
  }
}

extern "C" void kernel_launch(void* const* d_in, const int* in_sizes, int n_in,
                              void* d_out, int out_size, void* d_ws, size_t ws_size,
                              hipStream_t stream) {
  const float* x0 = (const float*)d_in[0];
  const int*   ei = (const int*)d_in[1];
  const int*   ci = (const int*)d_in[2];
  const float* Wc = (const float*)d_in[3];
  const float* bc = (const float*)d_in[4];
  const float* Wt = (const float*)d_in[5];
  const float* bt = (const float*)d_in[6];
  float* out = (float*)d_out;

  int n  = in_sizes[0] / DFEAT;     // 100000
  int E  = in_sizes[1] / 2;         // 600000
  int EC = in_sizes[2] / 2;         // 200000
  int etot = E + EC;

  const int* e_src = ei;
  const int* e_dst = ei + E;
  const int* c_src = ci;
  const int* c_dst = ci + EC;

  char* p = (char*)d_ws;
  ushort* xhA = (ushort*)p; p += (size_t)n * DFEAT * 2;
  ushort* xhB = (ushort*)p; p += (size_t)n * DFEAT * 2;
  ushort* wT  = (ushort*)p; p += (size_t)8 * DFEAT * DFEAT * 2;
  float* dall = (float*)p; p += (size_t)2 * n * 4;
  int* cnt_c = (int*)p; p += (size_t)n * 4;     // histogram -> cursor
  int* cnt_t = (int*)p; p += (size_t)n * 4;     // histogram
  int* rp    = (int*)p; p += (size_t)(n + 1) * 4;
  int* csr   = (int*)p; p += (size_t)etot * 4;
  float* wv  = (float*)p; p += (size_t)etot * 4;
  int* bsum  = (int*)p;

  int nb_n     = (n + NT - 1) / NT;
  int nb_scan  = (n + SCAN_ELEMS - 1) / SCAN_ELEMS;
  int nb_fused = (n + 63) / 64;

  // ---- build merged CSR + dinv + per-edge weights once per launch ----
  zero_k<<<(2 * n + NT - 1) / NT, NT, 0, stream>>>(cnt_c, 2 * n);
  hist2_k<<<(etot + NT - 1) / NT, NT, 0, stream>>>(e_dst, E, c_dst, EC, cnt_c, cnt_t);
  dinv2_k<<<nb_n, NT, 0, stream>>>(cnt_c, cnt_t, dall, n);
  scan_partial_m<<<nb_scan, NT, 0, stream>>>(cnt_c, cnt_t, n, bsum);
  scan_offsets_m<<<1, NT, 0, stream>>>(bsum, nb_scan, rp, n);
  scan_final_m<<<nb_scan, NT, 0, stream>>>(cnt_c, cnt_t, n, bsum, rp);
  fill_k<<<(etot + NT - 1) / NT, NT, 0, stream>>>(e_src, e_dst, E, c_src, c_dst, EC,
                                                  cnt_c, csr);
  wv_k<<<(etot + NT - 1) / NT, NT, 0, stream>>>(csr, dall, wv, etot, n);

  // ---- bf16 conversions ----
  convx_k<<<(n * 32 + NT - 1) / NT, NT, 0, stream>>>(x0, xhA, n * 32);
  convw_k<<<(8 * DFEAT * DFEAT) / NT, NT, 0, stream>>>(Wc, Wt, wT);

  // ---- layers: fused gather+GEMM, ping-ponged activations ----
  ushort* bin = xhA;
  ushort* bout = xhB;
  for (int i = 0; i < 4; i++) {
    aggemm_k<<<nb_fused, NT, 0, stream>>>(bin, rp, csr, wv, dall,
                                          wT + (size_t)i * DFEAT * DFEAT,
                                          wT + (size_t)(4 + i) * DFEAT * DFEAT,
                                          bc + i * DFEAT, bt + i * DFEAT,
                                          out, bout, n, (i == 3) ? 1 : 0);
    ushort* t = bin; bin = bout; bout = t;
  }
}